// Round 7
// baseline (194.242 us; speedup 1.0000x reference)
//
#include <hip/hip_runtime.h>
#include <hip/hip_bf16.h>

#define N_NODES 4096
#define HDIM    128
#define E1      131072
#define E2      131072
#define NMSG_B2B (2 * E1)
#define CAPB    192
#define CAPP    96
#define STGB    128
#define STGP    64

// ---- workspace layout (float units) ----
// ws[0..7] header (ws[3]=fused completion counter). Host memset zeroes [0, OFF_RED).
#define OFF_CNTB   8
#define OFF_CNTP   (OFF_CNTB + 4096)
#define OFF_RED    (OFF_CNTP + 4096)                 // 96 partial slots (32 b2b|32 p2b|32 area)
#define OFF_PSUM   (OFF_RED + 96)
#define OFF_PMAX   (OFF_PSUM + 128)
#define OFF_HB     (OFF_PMAX + 128)                  // h bf16: 524288 u16
#define OFF_P      (OFF_HB + 262144)                 // P (il layout) f32 [4096][128]
#define OFF_Q      (OFF_P + 524288)
#define OFF_R      (OFF_Q + 524288)
#define OFF_CP     (OFF_R + 524288)                  // (unused now)
#define OFF_B2H    (OFF_CP + 24576)
#define OFF_B2L    (OFF_B2H + 8192)
#define OFF_P2H    (OFF_B2L + 8192)
#define OFF_P2L    (OFF_P2H + 8192)
#define OFF_SWP    (OFF_P2L + 8192)
#define OFF_IW1    (OFF_SWP + 8192)                  // (unused now)
#define OFF_IW2    (OFF_IW1 + 4096)                  // (unused now)
#define OFF_WLAST  (OFF_IW2 + 8192)                  // il layout f32[128]
#define OFF_PEXTRA (OFF_WLAST + 128)                 // 3 rows, il layout
#define OFF_BKB    (OFF_PEXTRA + 384)                // uint2[4096*CAPB]: {oth, f32 w_raw}
#define OFF_BKP    (OFF_BKB + 2 * N_NODES * CAPB)    // uint2[4096*CAPP]: {bf16x2 pins, f32 w_raw}
#define WS_FLOATS  (OFF_BKP + 2 * N_NODES * CAPP)

typedef short short8 __attribute__((ext_vector_type(8)));
typedef float f32x4 __attribute__((ext_vector_type(4)));

__device__ __forceinline__ unsigned short f2bf(float f) {
  union { float f; unsigned u; } v; v.f = f;
  unsigned r = v.u + 0x7fffu + ((v.u >> 16) & 1u);   // RNE
  return (unsigned short)(r >> 16);
}
__device__ __forceinline__ float bf2f(unsigned short h) {
  return __uint_as_float((unsigned)h << 16);
}
__device__ __forceinline__ int il(int c) { return ((c & 63) << 1) | (c >> 6); }
__device__ __forceinline__ f32x4 relu4(f32x4 v) {
  f32x4 r;
  r[0] = fmaxf(v[0], 0.f); r[1] = fmaxf(v[1], 0.f);
  r[2] = fmaxf(v[2], 0.f); r[3] = fmaxf(v[3], 0.f);
  return r;
}

// ====== prep: reduces + init + packing + scatter + node-MLP — all overlapped =========
// 1185 blocks x 512 thr. Sections are mutually independent (MLP reads RAW weights with
// inline f2bf conversion, so it no longer waits on the packing section).
__global__ __launch_bounds__(512) void prep_kernel(const float* __restrict__ b2bw,
                                                   const float* __restrict__ p2bw,
                                                   const float* __restrict__ area,
                                                   const float* __restrict__ bW1,
                                                   const float* __restrict__ bW2,
                                                   const float* __restrict__ pW1,
                                                   const float* __restrict__ pW2,
                                                   const float* __restrict__ sWm,
                                                   const float* __restrict__ iW1,
                                                   const float* __restrict__ iW2,
                                                   const int* __restrict__ src,
                                                   const int* __restrict__ dst,
                                                   const int* __restrict__ pblk,
                                                   const int* __restrict__ ppin,
                                                   const float* __restrict__ pins,
                                                   const float* __restrict__ bfeat,
                                                   const int* __restrict__ rid,
                                                   const float* __restrict__ remb,
                                                   const float* __restrict__ iemb,
                                                   const float* __restrict__ ib1,
                                                   const float* __restrict__ ib2,
                                                   const float* __restrict__ bb1,
                                                   const float* __restrict__ pb1,
                                                   float* __restrict__ ws,
                                                   unsigned short* __restrict__ hb) {
  int b = blockIdx.x, t = threadIdx.x;
  if (b < 96) {                            // ---- partial reductions ----
    __shared__ float red[512];
    if (b < 32) {
      float m = 0.f;
      for (int i = b * 512 + t; i < E1; i += 32 * 512) m = fmaxf(m, fabsf(b2bw[i]));
      red[t] = m; __syncthreads();
      for (int s = 256; s > 0; s >>= 1) { if (t < s) red[t] = fmaxf(red[t], red[t + s]); __syncthreads(); }
      if (t == 0) ws[OFF_RED + b] = red[0];
    } else if (b < 64) {
      float m = 0.f;
      for (int i = (b - 32) * 512 + t; i < E2; i += 32 * 512) m = fmaxf(m, fabsf(p2bw[i]));
      red[t] = m; __syncthreads();
      for (int s = 256; s > 0; s >>= 1) { if (t < s) red[t] = fmaxf(red[t], red[t + s]); __syncthreads(); }
      if (t == 0) ws[OFF_RED + b] = red[0];
    } else {
      float s0 = 0.f;
      for (int i = (b - 64) * 512 + t; i < N_NODES; i += 32 * 512) s0 += area[i];
      red[t] = s0; __syncthreads();
      for (int s = 256; s > 0; s >>= 1) { if (t < s) red[t] += red[t + s]; __syncthreads(); }
      if (t == 0) ws[OFF_RED + b] = red[0];
    }
    return;
  }
  if (b == 96) {                           // ---- pool-accumulator init ----
    if (t < HDIM) {
      ws[OFF_PSUM + t] = 0.f;
      ((int*)ws)[OFF_PMAX + t] = 0x80000000;
    }
    return;
  }
  if (b < 161) {                           // ---- packing (64 blocks): fused-side weights
    unsigned short* B2h = (unsigned short*)(ws + OFF_B2H);
    unsigned short* B2l = (unsigned short*)(ws + OFF_B2L);
    unsigned short* P2h = (unsigned short*)(ws + OFF_P2H);
    unsigned short* P2l = (unsigned short*)(ws + OFF_P2L);
    unsigned short* Swp = (unsigned short*)(ws + OFF_SWP);
    float* wlast = ws + OFF_WLAST;
    float* pextra = ws + OFF_PEXTRA;
    const int total = 82432;
    for (int x = (b - 97) * 512 + t; x < total; x += 64 * 512) {
      if (x < 65536) {                     // b2h/b2l/p2h/p2l
        int u = x & 16383, which = x >> 14;
        int j = u & 7, lane = (u >> 3) & 63, ks = (u >> 9) & 3, nt = u >> 11;
        int n = nt * 16 + (lane & 15), k = ks * 32 + (lane >> 4) * 8 + j;
        float v = (which < 2) ? bW2[k * 128 + n] : pW2[k * 128 + n];
        unsigned short hi = f2bf(v);
        unsigned short outv = (which & 1) ? f2bf(v - bf2f(hi)) : hi;
        ((which < 2) ? ((which & 1) ? B2l : B2h) : ((which & 1) ? P2l : P2h))[u] = outv;
      } else if (x < 81920) {              // self_W
        int u = x - 65536;
        int j = u & 7, lane = (u >> 3) & 63, ks = (u >> 9) & 3, nt = u >> 11;
        int n = nt * 16 + (lane & 15), k = ks * 32 + (lane >> 4) * 8 + j;
        Swp[u] = f2bf(sWm[k * 128 + n]);
      } else if (x < 82048) {
        int c = x - 81920;
        wlast[il(c)] = bW1[256 * 128 + c];
      } else {
        int u = x - 82048;
        int r = u >> 7, c = u & 127;
        pextra[r * 128 + il(c)] = pW1[(128 + r) * 128 + c];
      }
    }
    return;
  }
  if (b < 929) {                           // ---- bucket scatter (768 blocks, 1 msg/thr)
    int i = (b - 161) * 512 + t;
    int* cntB = (int*)ws + OFF_CNTB;
    int* cntP = (int*)ws + OFF_CNTP;
    uint2* BKB = (uint2*)((int*)ws + OFF_BKB);
    uint2* BKP = (uint2*)((int*)ws + OFF_BKP);
    if (i < NMSG_B2B) {
      int e = i >> 1, d = i & 1;
      int tg = d ? dst[e] : src[e];
      int o  = d ? src[e] : dst[e];
      int pos = atomicAdd(&cntB[tg], 1);
      if (pos < CAPB) {
        uint2 v; v.x = (unsigned)o; v.y = __float_as_uint(b2bw[e]);
        BKB[tg * CAPB + pos] = v;
      }
    } else {
      int e = i - NMSG_B2B;
      int pin = ppin[e];
      int tg = pblk[e];
      int pos = atomicAdd(&cntP[tg], 1);
      if (pos < CAPP) {
        uint2 v;
        v.x = ((unsigned)f2bf(pins[pin * 2 + 1]) << 16) | (unsigned)f2bf(pins[pin * 2]);
        v.y = __float_as_uint(p2bw[e]);
        BKP[tg * CAPP + pos] = v;
      }
    }
    return;
  }
  // ---- node MLP + PQR (256 blocks, 16 nodes/block, 8 waves), inline weight cvt ----
  __shared__ __attribute__((aligned(16))) unsigned short xs[16 * 72];
  __shared__ __attribute__((aligned(16))) unsigned short h1s[16 * 136];
  __shared__ __attribute__((aligned(16))) unsigned short hs[16 * 136];
  float* P = ws + OFF_P;
  float* Q = ws + OFF_Q;
  float* R = ws + OFF_R;
  int n0 = (b - 929) * 16;
  for (int idx = t; idx < 1024; idx += 512) {
    int m = idx >> 6, c = idx & 63;
    int n = n0 + m;
    float v = 0.f;
    if (c < 16)      v = bfeat[n * 16 + c];
    else if (c < 32) v = remb[rid[n] * 16 + (c - 16)];
    else if (c < 40) v = iemb[(n & 1023) * 8 + (c - 32)];
    xs[m * 72 + c] = f2bf(v);
  }
  __syncthreads();
  int lane = t & 63, wv = t >> 6;   // wv 0..7
  int l15 = lane & 15, q = lane >> 4;
  int nW = wv * 16 + l15;           // output column for W1/W2 fragments
  f32x4 zero = {0.f, 0.f, 0.f, 0.f};
  f32x4 a1 = zero;
#pragma unroll
  for (int ks = 0; ks < 2; ks++) {
    short8 af = *(const short8*)(&xs[l15 * 72 + ks * 32 + q * 8]);
    short8 bfr;
#pragma unroll
    for (int j = 0; j < 8; j++) {
      int k = ks * 32 + q * 8 + j;
      bfr[j] = (short)((k < 40) ? f2bf(iW1[k * 128 + nW]) : (unsigned short)0);
    }
    a1 = __builtin_amdgcn_mfma_f32_16x16x32_bf16(af, bfr, a1, 0, 0, 0);
  }
  {
    float bv = ib1[nW];
#pragma unroll
    for (int r = 0; r < 4; r++)
      h1s[(q * 4 + r) * 136 + nW] = f2bf(fmaxf(a1[r] + bv, 0.f));
  }
  __syncthreads();
  f32x4 a2 = zero;
#pragma unroll
  for (int ks = 0; ks < 4; ks++) {
    short8 af = *(const short8*)(&h1s[l15 * 136 + ks * 32 + q * 8]);
    short8 bfr;
#pragma unroll
    for (int j = 0; j < 8; j++) {
      int k = ks * 32 + q * 8 + j;
      bfr[j] = (short)f2bf(iW2[k * 128 + nW]);
    }
    a2 = __builtin_amdgcn_mfma_f32_16x16x32_bf16(af, bfr, a2, 0, 0, 0);
  }
  {
    float bv = ib2[nW];
#pragma unroll
    for (int r = 0; r < 4; r++) {
      unsigned short hv = f2bf(fmaxf(a2[r] + bv, 0.f));
      hs[(q * 4 + r) * 136 + nW] = hv;
      hb[(n0 + q * 4 + r) * 128 + nW] = hv;
    }
  }
  __syncthreads();
  f32x4 a3[3];
#pragma unroll
  for (int i = 0; i < 3; i++) a3[i] = zero;
#pragma unroll
  for (int ks = 0; ks < 4; ks++) {
    short8 af = *(const short8*)(&hs[l15 * 136 + ks * 32 + q * 8]);
#pragma unroll
    for (int j = 0; j < 3; j++) {
      int col = (3 * wv + j) * 16 + l15;
      const float* srcW;
      int c2;
      if (col < 128)      { srcW = bW1;             c2 = col; }
      else if (col < 256) { srcW = bW1 + 128 * 128; c2 = col - 128; }
      else                { srcW = pW1;             c2 = col - 256; }
      short8 bfr;
#pragma unroll
      for (int jj = 0; jj < 8; jj++) {
        int k = ks * 32 + q * 8 + jj;
        bfr[jj] = (short)f2bf(srcW[k * 128 + c2]);
      }
      a3[j] = __builtin_amdgcn_mfma_f32_16x16x32_bf16(af, bfr, a3[j], 0, 0, 0);
    }
  }
#pragma unroll
  for (int j = 0; j < 3; j++) {
    int col = (3 * wv + j) * 16 + l15;
    int arr = col >> 7, cc = col & 127;
    float bias = (arr == 0) ? bb1[cc] : ((arr == 2) ? pb1[cc] : 0.f);
    float* dstp = (arr == 0) ? P : ((arr == 1) ? Q : R);
    int ic = il(cc);
#pragma unroll
    for (int r = 0; r < 4; r++)
      dstp[(n0 + q * 4 + r) * 128 + ic] = a3[j][r] + bias;
  }
}

// ======== fused (256 blocks x 1024 thr): LDS buckets + 8-deep gather pipeline =========
__global__ __launch_bounds__(1024) void fused_kernel(const unsigned short* __restrict__ hb,
                                                     const float* __restrict__ sb,
                                                     const float* __restrict__ lng,
                                                     const float* __restrict__ lnb,
                                                     const float* __restrict__ bb2,
                                                     const float* __restrict__ pb2,
                                                     const float* __restrict__ gW1,
                                                     const float* __restrict__ gb1,
                                                     const float* __restrict__ gW2,
                                                     const float* __restrict__ gb2,
                                                     float* __restrict__ ws,
                                                     float* __restrict__ out) {
  __shared__ __attribute__((aligned(16))) unsigned short A[16 * 648];  // h|Sbh|Sbl|Sph|Spl
  __shared__ __attribute__((aligned(16))) union {
    struct { float zp[2][16 * 128]; float zs[16 * 133]; } t;           // post-edge
    struct { uint2 bkb[16][STGB]; uint2 bkp[16][STGP]; } e;            // edge-phase staging
  } U;
  __shared__ float muS[16], rsg[16];
  __shared__ float partS[16][16], partQ[16][16];
  __shared__ float psumL[8][128];
  __shared__ int   pmaxL[8][128];
  __shared__ float sInvB, sInvP, sInvC;
  __shared__ int   isLast;
  int tid = threadIdx.x;
  int n0 = blockIdx.x * 16;
  int lane = tid & 63, wv = tid >> 6;   // 16 waves
  const int* cntBp = (const int*)ws + OFF_CNTB;
  const int* cntPp = (const int*)ws + OFF_CNTP;
  const uint2* BKB = (const uint2*)((const int*)ws + OFF_BKB);
  const uint2* BKP = (const uint2*)((const int*)ws + OFF_BKP);
  // stage h rows
  if (tid < 256) {
    int m = tid >> 4, o = (tid & 15) * 8;
    *(uint4*)(&A[m * 648 + o]) = *(const uint4*)(hb + (n0 + m) * 128 + o);
  }
  // cooperative bucket staging: all 1024 threads burst-load bucket lists into LDS
  for (int idx = tid; idx < 16 * STGB; idx += 1024) {
    int m = idx >> 7, j = idx & (STGB - 1);
    if (j < cntBp[n0 + m]) U.e.bkb[m][j] = BKB[(n0 + m) * CAPB + j];
  }
  {
    int m = tid >> 6, j = tid & (STGP - 1);
    if (tid < 16 * STGP && j < cntPp[n0 + m]) U.e.bkp[m][j] = BKP[(n0 + m) * CAPP + j];
  }
  // reduce the 96 partial slots -> invb / invp / invc
  if (tid < 96) {
    float v = ws[OFF_RED + tid];
    if (tid < 64) {
#pragma unroll
      for (int s = 1; s < 32; s <<= 1) v = fmaxf(v, __shfl_xor(v, s, 64));
      if (tid == 0)  sInvB = 1.f / fmaxf(v, 1.f);
      if (tid == 32) sInvP = 1.f / fmaxf(v, 1.f);
    } else {
#pragma unroll
      for (int s = 1; s < 32; s <<= 1) v += __shfl_xor(v, s, 64);
      if (tid == 64) {
        float cs = fmaxf(sqrtf(fmaxf(v, 1e-6f)), 1e-6f);
        sInvC = 1.f / cs;
      }
    }
  }
  int l5 = lane & 31, hf = lane >> 5;
  // il-storage float4 at 4*l5 decodes to channels {2l5, 2l5+64, 2l5+1, 2l5+65}
  f32x4 wl = *(const f32x4*)(ws + OFF_WLAST + 4 * l5);
  f32x4 e0 = *(const f32x4*)(ws + OFF_PEXTRA + 4 * l5);
  f32x4 e1 = *(const f32x4*)(ws + OFF_PEXTRA + 128 + 4 * l5);
  f32x4 e2 = *(const f32x4*)(ws + OFF_PEXTRA + 256 + 4 * l5);
  __syncthreads();
  // ---- edge accumulation: one node per wave, pairwise half-wave, 8 loads in flight ----
  {
    const float* Pm = ws + OFF_P;
    const float* Qm = ws + OFF_Q;
    const float* Rm = ws + OFF_R;
    float invb = sInvB, invp = sInvP, invc = sInvC;
    wl *= invb; e0 *= invc; e1 *= invc; e2 *= invp;
    int ln = wv;
    int node = n0 + ln;
    // ---- b2b: buckets from LDS; 16 msgs (8 pairs) per iter => 8 q-loads in flight ----
    {
      int cnt = min(cntBp[node], CAPB);
      int stg = min(cnt, STGB);
      const uint2* bkL = U.e.bkb[ln];
      const uint2* bkG = BKB + node * CAPB;
      f32x4 p4 = *(const f32x4*)(Pm + node * 128 + 4 * l5);
      f32x4 acc = {0.f, 0.f, 0.f, 0.f};
      int m = 0;
      for (; m + 16 <= stg; m += 16) {
        uint2 k0 = bkL[m + hf],      k1 = bkL[m + 2 + hf];
        uint2 k2 = bkL[m + 4 + hf],  k3 = bkL[m + 6 + hf];
        uint2 k4 = bkL[m + 8 + hf],  k5 = bkL[m + 10 + hf];
        uint2 k6 = bkL[m + 12 + hf], k7 = bkL[m + 14 + hf];
        f32x4 q0 = *(const f32x4*)(Qm + k0.x * 128 + 4 * l5);
        f32x4 q1 = *(const f32x4*)(Qm + k1.x * 128 + 4 * l5);
        f32x4 q2 = *(const f32x4*)(Qm + k2.x * 128 + 4 * l5);
        f32x4 q3 = *(const f32x4*)(Qm + k3.x * 128 + 4 * l5);
        f32x4 q4 = *(const f32x4*)(Qm + k4.x * 128 + 4 * l5);
        f32x4 q5 = *(const f32x4*)(Qm + k5.x * 128 + 4 * l5);
        f32x4 q6 = *(const f32x4*)(Qm + k6.x * 128 + 4 * l5);
        f32x4 q7 = *(const f32x4*)(Qm + k7.x * 128 + 4 * l5);
        acc += relu4(p4 + __uint_as_float(k0.y) * wl + q0);
        acc += relu4(p4 + __uint_as_float(k1.y) * wl + q1);
        acc += relu4(p4 + __uint_as_float(k2.y) * wl + q2);
        acc += relu4(p4 + __uint_as_float(k3.y) * wl + q3);
        acc += relu4(p4 + __uint_as_float(k4.y) * wl + q4);
        acc += relu4(p4 + __uint_as_float(k5.y) * wl + q5);
        acc += relu4(p4 + __uint_as_float(k6.y) * wl + q6);
        acc += relu4(p4 + __uint_as_float(k7.y) * wl + q7);
      }
      for (; m + 8 <= stg; m += 8) {
        uint2 k0 = bkL[m + hf],     k1 = bkL[m + 2 + hf];
        uint2 k2 = bkL[m + 4 + hf], k3 = bkL[m + 6 + hf];
        f32x4 q0 = *(const f32x4*)(Qm + k0.x * 128 + 4 * l5);
        f32x4 q1 = *(const f32x4*)(Qm + k1.x * 128 + 4 * l5);
        f32x4 q2 = *(const f32x4*)(Qm + k2.x * 128 + 4 * l5);
        f32x4 q3 = *(const f32x4*)(Qm + k3.x * 128 + 4 * l5);
        acc += relu4(p4 + __uint_as_float(k0.y) * wl + q0);
        acc += relu4(p4 + __uint_as_float(k1.y) * wl + q1);
        acc += relu4(p4 + __uint_as_float(k2.y) * wl + q2);
        acc += relu4(p4 + __uint_as_float(k3.y) * wl + q3);
      }
      for (; m + 2 <= stg; m += 2) {
        uint2 k = bkL[m + hf];
        f32x4 q = *(const f32x4*)(Qm + k.x * 128 + 4 * l5);
        acc += relu4(p4 + __uint_as_float(k.y) * wl + q);
      }
      if (m < stg) {                      // odd staged tail: half 1 masked out
        uint2 k = bkL[m + hf];
        f32x4 q = *(const f32x4*)(Qm + (k.x & (N_NODES - 1)) * 128 + 4 * l5);
        f32x4 v = relu4(p4 + __uint_as_float(k.y) * wl + q);
        if (hf == 0) acc += v;
        m++;
      }
      for (; m + 2 <= cnt; m += 2) {      // global remainder (rare)
        uint2 k = bkG[m + hf];
        f32x4 q = *(const f32x4*)(Qm + k.x * 128 + 4 * l5);
        acc += relu4(p4 + __uint_as_float(k.y) * wl + q);
      }
      if (m < cnt) {
        uint2 k = bkG[m + hf];
        f32x4 q = *(const f32x4*)(Qm + (k.x & (N_NODES - 1)) * 128 + 4 * l5);
        f32x4 v = relu4(p4 + __uint_as_float(k.y) * wl + q);
        if (hf == 0) acc += v;
      }
      f32x4 tot;
#pragma unroll
      for (int j = 0; j < 4; j++) tot[j] = acc[j] + __shfl_xor(acc[j], 32, 64);
      if (hf == 0) {
        unsigned short h0 = f2bf(tot[0]), h1 = f2bf(tot[1]);
        unsigned short h2 = f2bf(tot[2]), h3 = f2bf(tot[3]);
        *(unsigned*)(&A[ln * 648 + 128 + 2 * l5])      = (unsigned)h0 | ((unsigned)h2 << 16);
        *(unsigned*)(&A[ln * 648 + 128 + 64 + 2 * l5]) = (unsigned)h1 | ((unsigned)h3 << 16);
        unsigned short g0 = f2bf(tot[0] - bf2f(h0)), g1 = f2bf(tot[1] - bf2f(h1));
        unsigned short g2 = f2bf(tot[2] - bf2f(h2)), g3 = f2bf(tot[3] - bf2f(h3));
        *(unsigned*)(&A[ln * 648 + 256 + 2 * l5])      = (unsigned)g0 | ((unsigned)g2 << 16);
        *(unsigned*)(&A[ln * 648 + 256 + 64 + 2 * l5]) = (unsigned)g1 | ((unsigned)g3 << 16);
      }
    }
    // ---- p2b: LDS staged + global remainder, no gather ----
    {
      int cnt = min(cntPp[node], CAPP);
      int stg = min(cnt, STGP);
      const uint2* bkL = U.e.bkp[ln];
      const uint2* bkG = BKP + node * CAPP;
      f32x4 r4 = *(const f32x4*)(Rm + node * 128 + 4 * l5);
      f32x4 acc = {0.f, 0.f, 0.f, 0.f};
      int m = 0;
      for (; m + 4 <= stg; m += 4) {
        uint2 ka = bkL[m + hf], kb = bkL[m + 2 + hf];
        float a0 = __uint_as_float((ka.x & 0xFFFFu) << 16);
        float a1 = __uint_as_float(ka.x & 0xFFFF0000u);
        float a2 = __uint_as_float(ka.y);
        float b0 = __uint_as_float((kb.x & 0xFFFFu) << 16);
        float b1 = __uint_as_float(kb.x & 0xFFFF0000u);
        float b2 = __uint_as_float(kb.y);
        acc += relu4(r4 + a0 * e0 + a1 * e1 + a2 * e2);
        acc += relu4(r4 + b0 * e0 + b1 * e1 + b2 * e2);
      }
      for (; m + 2 <= stg; m += 2) {
        uint2 ka = bkL[m + hf];
        float a0 = __uint_as_float((ka.x & 0xFFFFu) << 16);
        float a1 = __uint_as_float(ka.x & 0xFFFF0000u);
        float a2 = __uint_as_float(ka.y);
        acc += relu4(r4 + a0 * e0 + a1 * e1 + a2 * e2);
      }
      if (m < stg) {
        uint2 ka = bkL[m + hf];
        float a0 = __uint_as_float((ka.x & 0xFFFFu) << 16);
        float a1 = __uint_as_float(ka.x & 0xFFFF0000u);
        float a2 = __uint_as_float(ka.y);
        f32x4 v = relu4(r4 + a0 * e0 + a1 * e1 + a2 * e2);
        if (hf == 0) acc += v;
        m++;
      }
      for (; m + 2 <= cnt; m += 2) {
        uint2 ka = bkG[m + hf];
        float a0 = __uint_as_float((ka.x & 0xFFFFu) << 16);
        float a1 = __uint_as_float(ka.x & 0xFFFF0000u);
        float a2 = __uint_as_float(ka.y);
        acc += relu4(r4 + a0 * e0 + a1 * e1 + a2 * e2);
      }
      if (m < cnt) {
        uint2 ka = bkG[m + hf];
        float a0 = __uint_as_float((ka.x & 0xFFFFu) << 16);
        float a1 = __uint_as_float(ka.x & 0xFFFF0000u);
        float a2 = __uint_as_float(ka.y);
        f32x4 v = relu4(r4 + a0 * e0 + a1 * e1 + a2 * e2);
        if (hf == 0) acc += v;
      }
      f32x4 tot;
#pragma unroll
      for (int j = 0; j < 4; j++) tot[j] = acc[j] + __shfl_xor(acc[j], 32, 64);
      if (hf == 0) {
        unsigned short h0 = f2bf(tot[0]), h1 = f2bf(tot[1]);
        unsigned short h2 = f2bf(tot[2]), h3 = f2bf(tot[3]);
        *(unsigned*)(&A[ln * 648 + 384 + 2 * l5])      = (unsigned)h0 | ((unsigned)h2 << 16);
        *(unsigned*)(&A[ln * 648 + 384 + 64 + 2 * l5]) = (unsigned)h1 | ((unsigned)h3 << 16);
        unsigned short g0 = f2bf(tot[0] - bf2f(h0)), g1 = f2bf(tot[1] - bf2f(h1));
        unsigned short g2 = f2bf(tot[2] - bf2f(h2)), g3 = f2bf(tot[3] - bf2f(h3));
        *(unsigned*)(&A[ln * 648 + 512 + 2 * l5])      = (unsigned)g0 | ((unsigned)g2 << 16);
        *(unsigned*)(&A[ln * 648 + 512 + 64 + 2 * l5]) = (unsigned)g1 | ((unsigned)g3 << 16);
      }
    }
  }
  __syncthreads();
  // ---- MFMA: 7 passes split across wave halves ----
  int l15 = lane & 15, q = lane >> 4;
  int ct = wv & 7, half = wv >> 3;
  f32x4 zero = {0.f, 0.f, 0.f, 0.f};
  f32x4 acc = zero;
  const unsigned short* bufs[7] = {
    (const unsigned short*)(ws + OFF_SWP), (const unsigned short*)(ws + OFF_B2H),
    (const unsigned short*)(ws + OFF_B2L), (const unsigned short*)(ws + OFF_B2H),
    (const unsigned short*)(ws + OFF_P2H), (const unsigned short*)(ws + OFF_P2L),
    (const unsigned short*)(ws + OFF_P2H)};
  const int segs[7] = {0, 128, 128, 256, 384, 384, 512};
  int p0 = half ? 4 : 0, p1 = half ? 7 : 4;
  for (int p = p0; p < p1; p++) {
#pragma unroll
    for (int ks = 0; ks < 4; ks++) {
      short8 af = *(const short8*)(&A[l15 * 648 + segs[p] + ks * 32 + q * 8]);
      short8 bfr = *(const short8*)(bufs[p] + ((ct * 4 + ks) * 64 + lane) * 8);
      acc = __builtin_amdgcn_mfma_f32_16x16x32_bf16(af, bfr, acc, 0, 0, 0);
    }
  }
  {
    int nn = ct * 16 + l15;
#pragma unroll
    for (int r = 0; r < 4; r++)
      U.t.zp[half][(q * 4 + r) * 128 + nn] = acc[r];
  }
  __syncthreads();
  // ---- combine partials + biases ----
  {
    int idx = tid;
    for (int rep = 0; rep < 2; rep++, idx += 1024) {
      int row = idx >> 7, c = idx & 127;
      float cb = (float)cntBp[n0 + row], cp = (float)cntPp[n0 + row];
      U.t.zs[row * 133 + c] = U.t.zp[0][row * 128 + c] + U.t.zp[1][row * 128 + c]
                            + sb[c] + cb * bb2[c] + cp * pb2[c];
    }
  }
  __syncthreads();
  if (tid < 256) {
    int r = tid >> 4, g = tid & 15;
    const float* zr = &U.t.zs[r * 133 + g * 8];
    float s = 0.f, s2 = 0.f;
#pragma unroll
    for (int i = 0; i < 8; i++) { float v = zr[i]; s += v; s2 += v * v; }
    partS[r][g] = s; partQ[r][g] = s2;
  }
  __syncthreads();
  if (tid < 16) {
    float s = 0.f, s2 = 0.f;
#pragma unroll
    for (int g = 0; g < 16; g++) { s += partS[tid][g]; s2 += partQ[tid][g]; }
    float m = s * (1.f / 128.f);
    float var = s2 * (1.f / 128.f) - m * m;
    muS[tid] = m;
    rsg[tid] = rsqrtf(fmaxf(var, 0.f) + 1e-5f);
  }
  __syncthreads();
  {
    int c = tid & 127, grp = tid >> 7;   // grp 0..7, 2 rows each
    float g = lng[c], b = lnb[c];
    float ls = 0.f; int lm = 0x80000000;
    for (int r = grp * 2; r < grp * 2 + 2; r++) {
      float v = (U.t.zs[r * 133 + c] - muS[r]) * rsg[r] * g + b;
      out[(n0 + r) * 128 + c] = v;
      ls += v;
      int e = __float_as_int(v);
      e = e >= 0 ? e : (e ^ 0x7fffffff);
      lm = max(lm, e);
    }
    psumL[grp][c] = ls; pmaxL[grp][c] = lm;
  }
  __syncthreads();
  if (tid < 128) {
    float s = 0.f; int mx = 0x80000000;
#pragma unroll
    for (int g = 0; g < 8; g++) { s += psumL[g][tid]; mx = max(mx, pmaxL[g][tid]); }
    atomicAdd(&ws[OFF_PSUM + tid], s);
    atomicMax(&((int*)ws)[OFF_PMAX + tid], mx);
  }
  if (tid < 16) out[N_NODES * HDIM + HDIM + n0 + tid] = 1.0f;
  // ---- graph-embedding tail: last block only ----
  __syncthreads();
  if (tid == 0) {
    __threadfence();
    int v = atomicAdd(&((int*)ws)[3], 1);
    isLast = (v == (int)gridDim.x - 1);
  }
  __syncthreads();
  if (!isLast) return;
  __shared__ float pooled[256];
  __shared__ float gpart[8][128];
  __shared__ float g1[128];
  if (tid < 128) {
    pooled[tid] = atomicAdd(&ws[OFF_PSUM + tid], 0.f) * (1.f / (float)N_NODES);
  } else if (tid < 256) {
    int e = atomicAdd(&((int*)ws)[OFF_PMAX + (tid - 128)], 0);
    int bits = e >= 0 ? e : (e ^ 0x7fffffff);
    pooled[tid] = __int_as_float(bits);
  }
  __syncthreads();
  {
    int c = tid & 127, g = tid >> 7;   // g 0..7
    float acc2 = 0.f;
#pragma unroll 8
    for (int k = g * 32; k < g * 32 + 32; k++) acc2 += pooled[k] * gW1[k * 128 + c];
    gpart[g][c] = acc2;
  }
  __syncthreads();
  if (tid < 128) {
    float s = gb1[tid];
#pragma unroll
    for (int g = 0; g < 8; g++) s += gpart[g][tid];
    g1[tid] = fmaxf(s, 0.f);
  }
  __syncthreads();
  {
    int c = tid & 127, g = tid >> 7;
    float acc2 = 0.f;
#pragma unroll 8
    for (int k = g * 16; k < g * 16 + 16; k++) acc2 += g1[k] * gW2[k * 128 + c];
    gpart[g][c] = acc2;
  }
  __syncthreads();
  if (tid < 128) {
    float s = gb2[tid];
#pragma unroll
    for (int g = 0; g < 8; g++) s += gpart[g][tid];
    out[N_NODES * HDIM + tid] = s;
  }
}

extern "C" void kernel_launch(void* const* d_in, const int* in_sizes, int n_in,
                              void* d_out, int out_size, void* d_ws, size_t ws_size,
                              hipStream_t stream) {
  const float* bfeat = (const float*)d_in[0];
  const int*   rid   = (const int*)d_in[1];
  const int*   bsrc  = (const int*)d_in[2];
  const int*   bdst  = (const int*)d_in[3];
  const float* bw    = (const float*)d_in[4];
  const int*   ppin  = (const int*)d_in[5];
  const int*   pblk  = (const int*)d_in[6];
  const float* pw    = (const float*)d_in[7];
  const float* pins  = (const float*)d_in[8];
  const float* area  = (const float*)d_in[9];
  const float* remb  = (const float*)d_in[10];
  const float* iemb  = (const float*)d_in[11];
  const float* inW1  = (const float*)d_in[12];
  const float* inb1  = (const float*)d_in[13];
  const float* inW2  = (const float*)d_in[14];
  const float* inb2  = (const float*)d_in[15];
  const float* bW1   = (const float*)d_in[16];
  const float* bb1   = (const float*)d_in[17];
  const float* bW2   = (const float*)d_in[18];
  const float* bb2   = (const float*)d_in[19];
  const float* pW1   = (const float*)d_in[20];
  const float* pb1   = (const float*)d_in[21];
  const float* pW2   = (const float*)d_in[22];
  const float* pb2   = (const float*)d_in[23];
  const float* sW    = (const float*)d_in[24];
  const float* sb    = (const float*)d_in[25];
  const float* lng   = (const float*)d_in[26];
  const float* lnb   = (const float*)d_in[27];
  const float* gW1   = (const float*)d_in[28];
  const float* gb1   = (const float*)d_in[29];
  const float* gW2   = (const float*)d_in[30];
  const float* gb2   = (const float*)d_in[31];

  float* ws  = (float*)d_ws;
  float* out = (float*)d_out;
  unsigned short* hb = (unsigned short*)(ws + OFF_HB);

  hipMemsetAsync(d_ws, 0, OFF_RED * sizeof(float), stream);   // header + cntB + cntP
  prep_kernel<<<1185, 512, 0, stream>>>(bw, pw, area,
                                        bW1, bW2, pW1, pW2, sW, inW1, inW2,
                                        bsrc, bdst, pblk, ppin, pins,
                                        bfeat, rid, remb, iemb, inb1, inb2, bb1, pb1,
                                        ws, hb);
  fused_kernel<<<256, 1024, 0, stream>>>(hb, sb, lng, lnb, bb2, pb2,
                                         gW1, gb1, gW2, gb2, ws, out);
}

// Round 8
// 183.212 us; speedup vs baseline: 1.0602x; 1.0602x over previous
//
#include <hip/hip_runtime.h>
#include <hip/hip_bf16.h>

#define N_NODES 4096
#define HDIM    128
#define E1      131072
#define E2      131072
#define NMSG_B2B (2 * E1)
#define CAPB    192
#define CAPP    96
#define STGB    128
#define STGP    64

// ---- workspace layout (float units) ----
// ws[0..7] header (ws[3]=fused completion counter). Host memset zeroes [0, OFF_RED).
#define OFF_CNTB   8
#define OFF_CNTP   (OFF_CNTB + 4096)
#define OFF_RED    (OFF_CNTP + 4096)                 // 96 partial slots (32 b2b|32 p2b|32 area)
#define OFF_PSUM   (OFF_RED + 96)                    // 4 banks x 128
#define OFF_PMAX   (OFF_PSUM + 512)                  // 4 banks x 128
#define OFF_HB     (OFF_PMAX + 512)                  // h bf16: 524288 u16
#define OFF_P      (OFF_HB + 262144)                 // P (il layout) f32 [4096][128]
#define OFF_Q      (OFF_P + 524288)
#define OFF_R      (OFF_Q + 524288)
#define OFF_CP     (OFF_R + 524288)                  // W1cat pack 49152 u16
#define OFF_B2H    (OFF_CP + 24576)
#define OFF_B2L    (OFF_B2H + 8192)
#define OFF_P2H    (OFF_B2L + 8192)
#define OFF_P2L    (OFF_P2H + 8192)
#define OFF_SWP    (OFF_P2L + 8192)
#define OFF_IW1    (OFF_SWP + 8192)
#define OFF_IW2    (OFF_IW1 + 4096)
#define OFF_WLAST  (OFF_IW2 + 8192)                  // il layout f32[128]
#define OFF_PEXTRA (OFF_WLAST + 128)                 // 3 rows, il layout
#define OFF_BKB    (OFF_PEXTRA + 384)                // uint2[4096*CAPB]: {oth, f32 w_raw}
#define OFF_BKP    (OFF_BKB + 2 * N_NODES * CAPB)    // uint2[4096*CAPP]: {bf16x2 pins, f32 w_raw}
#define WS_FLOATS  (OFF_BKP + 2 * N_NODES * CAPP)

typedef short short8 __attribute__((ext_vector_type(8)));
typedef float f32x4 __attribute__((ext_vector_type(4)));

__device__ __forceinline__ unsigned short f2bf(float f) {
  union { float f; unsigned u; } v; v.f = f;
  unsigned r = v.u + 0x7fffu + ((v.u >> 16) & 1u);   // RNE
  return (unsigned short)(r >> 16);
}
__device__ __forceinline__ float bf2f(unsigned short h) {
  return __uint_as_float((unsigned)h << 16);
}
__device__ __forceinline__ int il(int c) { return ((c & 63) << 1) | (c >> 6); }
__device__ __forceinline__ f32x4 relu4(f32x4 v) {
  f32x4 r;
  r[0] = fmaxf(v[0], 0.f); r[1] = fmaxf(v[1], 0.f);
  r[2] = fmaxf(v[2], 0.f); r[3] = fmaxf(v[3], 0.f);
  return r;
}

// ====== setup: partial reduces + init + weight packing + bucket scatter (1761 blocks) ==
__global__ __launch_bounds__(256) void setup_kernel(const float* __restrict__ b2bw,
                                                    const float* __restrict__ p2bw,
                                                    const float* __restrict__ area,
                                                    const float* __restrict__ bW1,
                                                    const float* __restrict__ bW2,
                                                    const float* __restrict__ pW1,
                                                    const float* __restrict__ pW2,
                                                    const float* __restrict__ sWm,
                                                    const float* __restrict__ iW1,
                                                    const float* __restrict__ iW2,
                                                    const int* __restrict__ src,
                                                    const int* __restrict__ dst,
                                                    const int* __restrict__ pblk,
                                                    const int* __restrict__ ppin,
                                                    const float* __restrict__ pins,
                                                    float* __restrict__ ws) {
  __shared__ float red[256];
  int b = blockIdx.x, t = threadIdx.x;
  if (b < 32) {
    float m = 0.f;
    for (int i = b * 256 + t; i < E1; i += 32 * 256) m = fmaxf(m, fabsf(b2bw[i]));
    red[t] = m; __syncthreads();
    for (int s = 128; s > 0; s >>= 1) { if (t < s) red[t] = fmaxf(red[t], red[t + s]); __syncthreads(); }
    if (t == 0) ws[OFF_RED + b] = red[0];
  } else if (b < 64) {
    float m = 0.f;
    for (int i = (b - 32) * 256 + t; i < E2; i += 32 * 256) m = fmaxf(m, fabsf(p2bw[i]));
    red[t] = m; __syncthreads();
    for (int s = 128; s > 0; s >>= 1) { if (t < s) red[t] = fmaxf(red[t], red[t + s]); __syncthreads(); }
    if (t == 0) ws[OFF_RED + b] = red[0];
  } else if (b < 96) {
    float s0 = 0.f;
    for (int i = (b - 64) * 256 + t; i < N_NODES; i += 32 * 256) s0 += area[i];
    red[t] = s0; __syncthreads();
    for (int s = 128; s > 0; s >>= 1) { if (t < s) red[t] += red[t + s]; __syncthreads(); }
    if (t == 0) ws[OFF_RED + b] = red[0];
  } else if (b == 96) {
    for (int i = t; i < 512; i += 256) {
      ws[OFF_PSUM + i] = 0.f;
      ((int*)ws)[OFF_PMAX + i] = 0x80000000;
    }
  } else if (b < 225) {                    // weight packing (128 blocks, grid-stride)
    unsigned short* Cp  = (unsigned short*)(ws + OFF_CP);
    unsigned short* B2h = (unsigned short*)(ws + OFF_B2H);
    unsigned short* B2l = (unsigned short*)(ws + OFF_B2L);
    unsigned short* P2h = (unsigned short*)(ws + OFF_P2H);
    unsigned short* P2l = (unsigned short*)(ws + OFF_P2L);
    unsigned short* Swp = (unsigned short*)(ws + OFF_SWP);
    unsigned short* I1p = (unsigned short*)(ws + OFF_IW1);
    unsigned short* I2p = (unsigned short*)(ws + OFF_IW2);
    float* wlast = ws + OFF_WLAST;
    float* pextra = ws + OFF_PEXTRA;
    const int total = 156160;
    for (int x = (b - 97) * 256 + t; x < total; x += 128 * 256) {
      if (x < 49152) {                     // W1cat: 24nt x 4ks -> [P|Q|R]
        int j = x & 7, lane = (x >> 3) & 63, ks = (x >> 9) & 3, nc = x >> 11;
        int col = nc * 16 + (lane & 15), k = ks * 32 + (lane >> 4) * 8 + j;
        float v;
        if (col < 128)      v = bW1[k * 128 + col];
        else if (col < 256) v = bW1[(128 + k) * 128 + (col - 128)];
        else                v = pW1[k * 128 + (col - 256)];
        Cp[x] = f2bf(v);
      } else if (x < 114688) {             // b2h/b2l/p2h/p2l
        int u = (x - 49152) & 16383, which = (x - 49152) >> 14;
        int j = u & 7, lane = (u >> 3) & 63, ks = (u >> 9) & 3, nt = u >> 11;
        int n = nt * 16 + (lane & 15), k = ks * 32 + (lane >> 4) * 8 + j;
        float v = (which < 2) ? bW2[k * 128 + n] : pW2[k * 128 + n];
        unsigned short hi = f2bf(v);
        unsigned short outv = (which & 1) ? f2bf(v - bf2f(hi)) : hi;
        ((which < 2) ? ((which & 1) ? B2l : B2h) : ((which & 1) ? P2l : P2h))[u] = outv;
      } else if (x < 131072) {             // self_W
        int u = x - 114688;
        int j = u & 7, lane = (u >> 3) & 63, ks = (u >> 9) & 3, nt = u >> 11;
        int n = nt * 16 + (lane & 15), k = ks * 32 + (lane >> 4) * 8 + j;
        Swp[u] = f2bf(sWm[k * 128 + n]);
      } else if (x < 139264) {             // in_W1 (K pad 40->64)
        int u = x - 131072;
        int j = u & 7, lane = (u >> 3) & 63, ks = (u >> 9) & 1, nt = u >> 10;
        int n = nt * 16 + (lane & 15), k = ks * 32 + (lane >> 4) * 8 + j;
        I1p[u] = (k < 40) ? f2bf(iW1[k * 128 + n]) : 0;
      } else if (x < 155648) {             // in_W2
        int u = x - 139264;
        int j = u & 7, lane = (u >> 3) & 63, ks = (u >> 9) & 3, nt = u >> 11;
        int n = nt * 16 + (lane & 15), k = ks * 32 + (lane >> 4) * 8 + j;
        I2p[u] = f2bf(iW2[k * 128 + n]);
      } else if (x < 155776) {
        int c = x - 155648;
        wlast[il(c)] = bW1[256 * 128 + c];
      } else {
        int u = x - 155776;
        int r = u >> 7, c = u & 127;
        pextra[r * 128 + il(c)] = pW1[(128 + r) * 128 + c];
      }
    }
  } else {                                 // bucket scatter (1536 blocks, 1 msg/thread)
    int i = (b - 225) * 256 + t;
    int* cntB = (int*)ws + OFF_CNTB;
    int* cntP = (int*)ws + OFF_CNTP;
    uint2* BKB = (uint2*)((int*)ws + OFF_BKB);
    uint2* BKP = (uint2*)((int*)ws + OFF_BKP);
    if (i < NMSG_B2B) {
      int e = i >> 1, d = i & 1;
      int tg = d ? dst[e] : src[e];
      int o  = d ? src[e] : dst[e];
      int pos = atomicAdd(&cntB[tg], 1);
      if (pos < CAPB) {
        uint2 v; v.x = (unsigned)o; v.y = __float_as_uint(b2bw[e]);
        BKB[tg * CAPB + pos] = v;
      }
    } else {
      int e = i - NMSG_B2B;
      int pin = ppin[e];
      int tg = pblk[e];
      int pos = atomicAdd(&cntP[tg], 1);
      if (pos < CAPP) {
        uint2 v;
        v.x = ((unsigned)f2bf(pins[pin * 2 + 1]) << 16) | (unsigned)f2bf(pins[pin * 2]);
        v.y = __float_as_uint(p2bw[e]);
        BKP[tg * CAPP + pos] = v;
      }
    }
  }
}

// ====== mid: node MLP + PQR only (256 blocks, 16 nodes/block, 8 waves) ================
__global__ __launch_bounds__(512) void mid_kernel(const float* __restrict__ bfeat,
                                                  const int* __restrict__ rid,
                                                  const float* __restrict__ remb,
                                                  const float* __restrict__ iemb,
                                                  const float* __restrict__ ib1,
                                                  const float* __restrict__ ib2,
                                                  const float* __restrict__ bb1,
                                                  const float* __restrict__ pb1,
                                                  float* __restrict__ ws,
                                                  unsigned short* __restrict__ hb) {
  __shared__ __attribute__((aligned(16))) unsigned short xs[16 * 72];
  __shared__ __attribute__((aligned(16))) unsigned short h1s[16 * 136];
  __shared__ __attribute__((aligned(16))) unsigned short hs[16 * 136];
  int tid = threadIdx.x;
  const unsigned short* I1p = (const unsigned short*)(ws + OFF_IW1);
  const unsigned short* I2p = (const unsigned short*)(ws + OFF_IW2);
  const unsigned short* Cp  = (const unsigned short*)(ws + OFF_CP);
  float* P = ws + OFF_P;
  float* Q = ws + OFF_Q;
  float* R = ws + OFF_R;
  int n0 = blockIdx.x * 16;
  for (int idx = tid; idx < 1024; idx += 512) {
    int m = idx >> 6, c = idx & 63;
    int n = n0 + m;
    float v = 0.f;
    if (c < 16)      v = bfeat[n * 16 + c];
    else if (c < 32) v = remb[rid[n] * 16 + (c - 16)];
    else if (c < 40) v = iemb[(n & 1023) * 8 + (c - 32)];
    xs[m * 72 + c] = f2bf(v);
  }
  __syncthreads();
  int lane = tid & 63, wv = tid >> 6;   // wv 0..7
  int l15 = lane & 15, q = lane >> 4;
  f32x4 zero = {0.f, 0.f, 0.f, 0.f};
  f32x4 a1 = zero;
#pragma unroll
  for (int ks = 0; ks < 2; ks++) {
    short8 af = *(const short8*)(&xs[l15 * 72 + ks * 32 + q * 8]);
    short8 bfr = *(const short8*)(I1p + ((wv * 2 + ks) * 64 + lane) * 8);
    a1 = __builtin_amdgcn_mfma_f32_16x16x32_bf16(af, bfr, a1, 0, 0, 0);
  }
  {
    int n = wv * 16 + l15;
    float b = ib1[n];
#pragma unroll
    for (int r = 0; r < 4; r++)
      h1s[(q * 4 + r) * 136 + n] = f2bf(fmaxf(a1[r] + b, 0.f));
  }
  __syncthreads();
  f32x4 a2 = zero;
#pragma unroll
  for (int ks = 0; ks < 4; ks++) {
    short8 af = *(const short8*)(&h1s[l15 * 136 + ks * 32 + q * 8]);
    short8 bfr = *(const short8*)(I2p + ((wv * 4 + ks) * 64 + lane) * 8);
    a2 = __builtin_amdgcn_mfma_f32_16x16x32_bf16(af, bfr, a2, 0, 0, 0);
  }
  {
    int n = wv * 16 + l15;
    float b = ib2[n];
#pragma unroll
    for (int r = 0; r < 4; r++) {
      unsigned short hv = f2bf(fmaxf(a2[r] + b, 0.f));
      hs[(q * 4 + r) * 136 + n] = hv;
      hb[(n0 + q * 4 + r) * 128 + n] = hv;
    }
  }
  __syncthreads();
  f32x4 a3[3];
#pragma unroll
  for (int i = 0; i < 3; i++) a3[i] = zero;
#pragma unroll
  for (int ks = 0; ks < 4; ks++) {
    short8 af = *(const short8*)(&hs[l15 * 136 + ks * 32 + q * 8]);
#pragma unroll
    for (int j = 0; j < 3; j++) {
      short8 bfr = *(const short8*)(Cp + (((3 * wv + j) * 4 + ks) * 64 + lane) * 8);
      a3[j] = __builtin_amdgcn_mfma_f32_16x16x32_bf16(af, bfr, a3[j], 0, 0, 0);
    }
  }
#pragma unroll
  for (int j = 0; j < 3; j++) {
    int col = (3 * wv + j) * 16 + l15;
    int arr = col >> 7, cc = col & 127;
    float bias = (arr == 0) ? bb1[cc] : ((arr == 2) ? pb1[cc] : 0.f);
    float* dstp = (arr == 0) ? P : ((arr == 1) ? Q : R);
    int ic = il(cc);
#pragma unroll
    for (int r = 0; r < 4; r++)
      dstp[(n0 + q * 4 + r) * 128 + ic] = a3[j][r] + bias;
  }
}

// ======== fused (256 blocks x 1024 thr): LDS buckets + 8-deep gather pipeline =========
__global__ __launch_bounds__(1024) void fused_kernel(const unsigned short* __restrict__ hb,
                                                     const float* __restrict__ sb,
                                                     const float* __restrict__ lng,
                                                     const float* __restrict__ lnb,
                                                     const float* __restrict__ bb2,
                                                     const float* __restrict__ pb2,
                                                     const float* __restrict__ gW1,
                                                     const float* __restrict__ gb1,
                                                     const float* __restrict__ gW2,
                                                     const float* __restrict__ gb2,
                                                     float* __restrict__ ws,
                                                     float* __restrict__ out) {
  __shared__ __attribute__((aligned(16))) unsigned short A[16 * 648];  // h|Sbh|Sbl|Sph|Spl
  __shared__ __attribute__((aligned(16))) union {
    struct { float zp[2][16 * 128]; float zs[16 * 133]; } t;           // post-edge
    struct { uint2 bkb[16][STGB]; uint2 bkp[16][STGP]; } e;            // edge-phase staging
  } U;
  __shared__ float muS[16], rsg[16];
  __shared__ float partS[16][16], partQ[16][16];
  __shared__ float psumL[8][128];
  __shared__ int   pmaxL[8][128];
  __shared__ float sInvB, sInvP, sInvC;
  __shared__ int   isLast;
  int tid = threadIdx.x;
  int n0 = blockIdx.x * 16;
  int lane = tid & 63, wv = tid >> 6;   // 16 waves
  const int* cntBp = (const int*)ws + OFF_CNTB;
  const int* cntPp = (const int*)ws + OFF_CNTP;
  const uint2* BKB = (const uint2*)((const int*)ws + OFF_BKB);
  const uint2* BKP = (const uint2*)((const int*)ws + OFF_BKP);
  // stage h rows
  if (tid < 256) {
    int m = tid >> 4, o = (tid & 15) * 8;
    *(uint4*)(&A[m * 648 + o]) = *(const uint4*)(hb + (n0 + m) * 128 + o);
  }
  // cooperative bucket staging: all 1024 threads burst-load bucket lists into LDS
  for (int idx = tid; idx < 16 * STGB; idx += 1024) {
    int m = idx >> 7, j = idx & (STGB - 1);
    if (j < cntBp[n0 + m]) U.e.bkb[m][j] = BKB[(n0 + m) * CAPB + j];
  }
  {
    int m = tid >> 6, j = tid & (STGP - 1);
    if (tid < 16 * STGP && j < cntPp[n0 + m]) U.e.bkp[m][j] = BKP[(n0 + m) * CAPP + j];
  }
  // reduce the 96 partial slots -> invb / invp / invc
  if (tid < 96) {
    float v = ws[OFF_RED + tid];
    if (tid < 64) {
#pragma unroll
      for (int s = 1; s < 32; s <<= 1) v = fmaxf(v, __shfl_xor(v, s, 64));
      if (tid == 0)  sInvB = 1.f / fmaxf(v, 1.f);
      if (tid == 32) sInvP = 1.f / fmaxf(v, 1.f);
    } else {
#pragma unroll
      for (int s = 1; s < 32; s <<= 1) v += __shfl_xor(v, s, 64);
      if (tid == 64) {
        float cs = fmaxf(sqrtf(fmaxf(v, 1e-6f)), 1e-6f);
        sInvC = 1.f / cs;
      }
    }
  }
  int l5 = lane & 31, hf = lane >> 5;
  // il-storage float4 at 4*l5 decodes to channels {2l5, 2l5+64, 2l5+1, 2l5+65}
  f32x4 wl = *(const f32x4*)(ws + OFF_WLAST + 4 * l5);
  f32x4 e0 = *(const f32x4*)(ws + OFF_PEXTRA + 4 * l5);
  f32x4 e1 = *(const f32x4*)(ws + OFF_PEXTRA + 128 + 4 * l5);
  f32x4 e2 = *(const f32x4*)(ws + OFF_PEXTRA + 256 + 4 * l5);
  __syncthreads();
  // ---- edge accumulation: one node per wave, pairwise half-wave, 8 loads in flight ----
  {
    const float* Pm = ws + OFF_P;
    const float* Qm = ws + OFF_Q;
    const float* Rm = ws + OFF_R;
    float invb = sInvB, invp = sInvP, invc = sInvC;
    wl *= invb; e0 *= invc; e1 *= invc; e2 *= invp;
    int ln = wv;
    int node = n0 + ln;
    // ---- b2b: buckets from LDS; 16 msgs (8 pairs) per iter => 8 q-loads in flight ----
    {
      int cnt = min(cntBp[node], CAPB);
      int stg = min(cnt, STGB);
      const uint2* bkL = U.e.bkb[ln];
      const uint2* bkG = BKB + node * CAPB;
      f32x4 p4 = *(const f32x4*)(Pm + node * 128 + 4 * l5);
      f32x4 acc = {0.f, 0.f, 0.f, 0.f};
      int m = 0;
      for (; m + 16 <= stg; m += 16) {
        uint2 k0 = bkL[m + hf],      k1 = bkL[m + 2 + hf];
        uint2 k2 = bkL[m + 4 + hf],  k3 = bkL[m + 6 + hf];
        uint2 k4 = bkL[m + 8 + hf],  k5 = bkL[m + 10 + hf];
        uint2 k6 = bkL[m + 12 + hf], k7 = bkL[m + 14 + hf];
        f32x4 q0 = *(const f32x4*)(Qm + k0.x * 128 + 4 * l5);
        f32x4 q1 = *(const f32x4*)(Qm + k1.x * 128 + 4 * l5);
        f32x4 q2 = *(const f32x4*)(Qm + k2.x * 128 + 4 * l5);
        f32x4 q3 = *(const f32x4*)(Qm + k3.x * 128 + 4 * l5);
        f32x4 q4 = *(const f32x4*)(Qm + k4.x * 128 + 4 * l5);
        f32x4 q5 = *(const f32x4*)(Qm + k5.x * 128 + 4 * l5);
        f32x4 q6 = *(const f32x4*)(Qm + k6.x * 128 + 4 * l5);
        f32x4 q7 = *(const f32x4*)(Qm + k7.x * 128 + 4 * l5);
        acc += relu4(p4 + __uint_as_float(k0.y) * wl + q0);
        acc += relu4(p4 + __uint_as_float(k1.y) * wl + q1);
        acc += relu4(p4 + __uint_as_float(k2.y) * wl + q2);
        acc += relu4(p4 + __uint_as_float(k3.y) * wl + q3);
        acc += relu4(p4 + __uint_as_float(k4.y) * wl + q4);
        acc += relu4(p4 + __uint_as_float(k5.y) * wl + q5);
        acc += relu4(p4 + __uint_as_float(k6.y) * wl + q6);
        acc += relu4(p4 + __uint_as_float(k7.y) * wl + q7);
      }
      for (; m + 8 <= stg; m += 8) {
        uint2 k0 = bkL[m + hf],     k1 = bkL[m + 2 + hf];
        uint2 k2 = bkL[m + 4 + hf], k3 = bkL[m + 6 + hf];
        f32x4 q0 = *(const f32x4*)(Qm + k0.x * 128 + 4 * l5);
        f32x4 q1 = *(const f32x4*)(Qm + k1.x * 128 + 4 * l5);
        f32x4 q2 = *(const f32x4*)(Qm + k2.x * 128 + 4 * l5);
        f32x4 q3 = *(const f32x4*)(Qm + k3.x * 128 + 4 * l5);
        acc += relu4(p4 + __uint_as_float(k0.y) * wl + q0);
        acc += relu4(p4 + __uint_as_float(k1.y) * wl + q1);
        acc += relu4(p4 + __uint_as_float(k2.y) * wl + q2);
        acc += relu4(p4 + __uint_as_float(k3.y) * wl + q3);
      }
      for (; m + 2 <= stg; m += 2) {
        uint2 k = bkL[m + hf];
        f32x4 q = *(const f32x4*)(Qm + k.x * 128 + 4 * l5);
        acc += relu4(p4 + __uint_as_float(k.y) * wl + q);
      }
      if (m < stg) {                      // odd staged tail: half 1 masked out
        uint2 k = bkL[m + hf];
        f32x4 q = *(const f32x4*)(Qm + (k.x & (N_NODES - 1)) * 128 + 4 * l5);
        f32x4 v = relu4(p4 + __uint_as_float(k.y) * wl + q);
        if (hf == 0) acc += v;
        m++;
      }
      for (; m + 2 <= cnt; m += 2) {      // global remainder (rare)
        uint2 k = bkG[m + hf];
        f32x4 q = *(const f32x4*)(Qm + k.x * 128 + 4 * l5);
        acc += relu4(p4 + __uint_as_float(k.y) * wl + q);
      }
      if (m < cnt) {
        uint2 k = bkG[m + hf];
        f32x4 q = *(const f32x4*)(Qm + (k.x & (N_NODES - 1)) * 128 + 4 * l5);
        f32x4 v = relu4(p4 + __uint_as_float(k.y) * wl + q);
        if (hf == 0) acc += v;
      }
      f32x4 tot;
#pragma unroll
      for (int j = 0; j < 4; j++) tot[j] = acc[j] + __shfl_xor(acc[j], 32, 64);
      if (hf == 0) {
        unsigned short h0 = f2bf(tot[0]), h1 = f2bf(tot[1]);
        unsigned short h2 = f2bf(tot[2]), h3 = f2bf(tot[3]);
        *(unsigned*)(&A[ln * 648 + 128 + 2 * l5])      = (unsigned)h0 | ((unsigned)h2 << 16);
        *(unsigned*)(&A[ln * 648 + 128 + 64 + 2 * l5]) = (unsigned)h1 | ((unsigned)h3 << 16);
        unsigned short g0 = f2bf(tot[0] - bf2f(h0)), g1 = f2bf(tot[1] - bf2f(h1));
        unsigned short g2 = f2bf(tot[2] - bf2f(h2)), g3 = f2bf(tot[3] - bf2f(h3));
        *(unsigned*)(&A[ln * 648 + 256 + 2 * l5])      = (unsigned)g0 | ((unsigned)g2 << 16);
        *(unsigned*)(&A[ln * 648 + 256 + 64 + 2 * l5]) = (unsigned)g1 | ((unsigned)g3 << 16);
      }
    }
    // ---- p2b: LDS staged + global remainder, no gather ----
    {
      int cnt = min(cntPp[node], CAPP);
      int stg = min(cnt, STGP);
      const uint2* bkL = U.e.bkp[ln];
      const uint2* bkG = BKP + node * CAPP;
      f32x4 r4 = *(const f32x4*)(Rm + node * 128 + 4 * l5);
      f32x4 acc = {0.f, 0.f, 0.f, 0.f};
      int m = 0;
      for (; m + 4 <= stg; m += 4) {
        uint2 ka = bkL[m + hf], kb = bkL[m + 2 + hf];
        float a0 = __uint_as_float((ka.x & 0xFFFFu) << 16);
        float a1 = __uint_as_float(ka.x & 0xFFFF0000u);
        float a2 = __uint_as_float(ka.y);
        float b0 = __uint_as_float((kb.x & 0xFFFFu) << 16);
        float b1 = __uint_as_float(kb.x & 0xFFFF0000u);
        float b2 = __uint_as_float(kb.y);
        acc += relu4(r4 + a0 * e0 + a1 * e1 + a2 * e2);
        acc += relu4(r4 + b0 * e0 + b1 * e1 + b2 * e2);
      }
      for (; m + 2 <= stg; m += 2) {
        uint2 ka = bkL[m + hf];
        float a0 = __uint_as_float((ka.x & 0xFFFFu) << 16);
        float a1 = __uint_as_float(ka.x & 0xFFFF0000u);
        float a2 = __uint_as_float(ka.y);
        acc += relu4(r4 + a0 * e0 + a1 * e1 + a2 * e2);
      }
      if (m < stg) {
        uint2 ka = bkL[m + hf];
        float a0 = __uint_as_float((ka.x & 0xFFFFu) << 16);
        float a1 = __uint_as_float(ka.x & 0xFFFF0000u);
        float a2 = __uint_as_float(ka.y);
        f32x4 v = relu4(r4 + a0 * e0 + a1 * e1 + a2 * e2);
        if (hf == 0) acc += v;
        m++;
      }
      for (; m + 2 <= cnt; m += 2) {
        uint2 ka = bkG[m + hf];
        float a0 = __uint_as_float((ka.x & 0xFFFFu) << 16);
        float a1 = __uint_as_float(ka.x & 0xFFFF0000u);
        float a2 = __uint_as_float(ka.y);
        acc += relu4(r4 + a0 * e0 + a1 * e1 + a2 * e2);
      }
      if (m < cnt) {
        uint2 ka = bkG[m + hf];
        float a0 = __uint_as_float((ka.x & 0xFFFFu) << 16);
        float a1 = __uint_as_float(ka.x & 0xFFFF0000u);
        float a2 = __uint_as_float(ka.y);
        f32x4 v = relu4(r4 + a0 * e0 + a1 * e1 + a2 * e2);
        if (hf == 0) acc += v;
      }
      f32x4 tot;
#pragma unroll
      for (int j = 0; j < 4; j++) tot[j] = acc[j] + __shfl_xor(acc[j], 32, 64);
      if (hf == 0) {
        unsigned short h0 = f2bf(tot[0]), h1 = f2bf(tot[1]);
        unsigned short h2 = f2bf(tot[2]), h3 = f2bf(tot[3]);
        *(unsigned*)(&A[ln * 648 + 384 + 2 * l5])      = (unsigned)h0 | ((unsigned)h2 << 16);
        *(unsigned*)(&A[ln * 648 + 384 + 64 + 2 * l5]) = (unsigned)h1 | ((unsigned)h3 << 16);
        unsigned short g0 = f2bf(tot[0] - bf2f(h0)), g1 = f2bf(tot[1] - bf2f(h1));
        unsigned short g2 = f2bf(tot[2] - bf2f(h2)), g3 = f2bf(tot[3] - bf2f(h3));
        *(unsigned*)(&A[ln * 648 + 512 + 2 * l5])      = (unsigned)g0 | ((unsigned)g2 << 16);
        *(unsigned*)(&A[ln * 648 + 512 + 64 + 2 * l5]) = (unsigned)g1 | ((unsigned)g3 << 16);
      }
    }
  }
  __syncthreads();
  // ---- MFMA: 7 passes split across wave halves ----
  int l15 = lane & 15, q = lane >> 4;
  int ct = wv & 7, half = wv >> 3;
  f32x4 zero = {0.f, 0.f, 0.f, 0.f};
  f32x4 acc = zero;
  const unsigned short* bufs[7] = {
    (const unsigned short*)(ws + OFF_SWP), (const unsigned short*)(ws + OFF_B2H),
    (const unsigned short*)(ws + OFF_B2L), (const unsigned short*)(ws + OFF_B2H),
    (const unsigned short*)(ws + OFF_P2H), (const unsigned short*)(ws + OFF_P2L),
    (const unsigned short*)(ws + OFF_P2H)};
  const int segs[7] = {0, 128, 128, 256, 384, 384, 512};
  int p0 = half ? 4 : 0, p1 = half ? 7 : 4;
  for (int p = p0; p < p1; p++) {
#pragma unroll
    for (int ks = 0; ks < 4; ks++) {
      short8 af = *(const short8*)(&A[l15 * 648 + segs[p] + ks * 32 + q * 8]);
      short8 bfr = *(const short8*)(bufs[p] + ((ct * 4 + ks) * 64 + lane) * 8);
      acc = __builtin_amdgcn_mfma_f32_16x16x32_bf16(af, bfr, acc, 0, 0, 0);
    }
  }
  {
    int nn = ct * 16 + l15;
#pragma unroll
    for (int r = 0; r < 4; r++)
      U.t.zp[half][(q * 4 + r) * 128 + nn] = acc[r];
  }
  __syncthreads();
  // ---- combine partials + biases ----
  {
    int idx = tid;
    for (int rep = 0; rep < 2; rep++, idx += 1024) {
      int row = idx >> 7, c = idx & 127;
      float cb = (float)cntBp[n0 + row], cp = (float)cntPp[n0 + row];
      U.t.zs[row * 133 + c] = U.t.zp[0][row * 128 + c] + U.t.zp[1][row * 128 + c]
                            + sb[c] + cb * bb2[c] + cp * pb2[c];
    }
  }
  __syncthreads();
  if (tid < 256) {
    int r = tid >> 4, g = tid & 15;
    const float* zr = &U.t.zs[r * 133 + g * 8];
    float s = 0.f, s2 = 0.f;
#pragma unroll
    for (int i = 0; i < 8; i++) { float v = zr[i]; s += v; s2 += v * v; }
    partS[r][g] = s; partQ[r][g] = s2;
  }
  __syncthreads();
  if (tid < 16) {
    float s = 0.f, s2 = 0.f;
#pragma unroll
    for (int g = 0; g < 16; g++) { s += partS[tid][g]; s2 += partQ[tid][g]; }
    float m = s * (1.f / 128.f);
    float var = s2 * (1.f / 128.f) - m * m;
    muS[tid] = m;
    rsg[tid] = rsqrtf(fmaxf(var, 0.f) + 1e-5f);
  }
  __syncthreads();
  {
    int c = tid & 127, grp = tid >> 7;   // grp 0..7, 2 rows each
    float g = lng[c], b = lnb[c];
    float ls = 0.f; int lm = 0x80000000;
    for (int r = grp * 2; r < grp * 2 + 2; r++) {
      float v = (U.t.zs[r * 133 + c] - muS[r]) * rsg[r] * g + b;
      out[(n0 + r) * 128 + c] = v;
      ls += v;
      int e = __float_as_int(v);
      e = e >= 0 ? e : (e ^ 0x7fffffff);
      lm = max(lm, e);
    }
    psumL[grp][c] = ls; pmaxL[grp][c] = lm;
  }
  __syncthreads();
  if (tid < 128) {
    float s = 0.f; int mx = 0x80000000;
#pragma unroll
    for (int g = 0; g < 8; g++) { s += psumL[g][tid]; mx = max(mx, pmaxL[g][tid]); }
    int bank = (blockIdx.x & 3) << 7;    // 4-way striped accumulators
    atomicAdd(&ws[OFF_PSUM + bank + tid], s);
    atomicMax(&((int*)ws)[OFF_PMAX + bank + tid], mx);
  }
  if (tid < 16) out[N_NODES * HDIM + HDIM + n0 + tid] = 1.0f;
  // ---- graph-embedding tail: last block only ----
  __syncthreads();
  if (tid == 0) {
    __threadfence();
    int v = atomicAdd(&((int*)ws)[3], 1);
    isLast = (v == (int)gridDim.x - 1);
  }
  __syncthreads();
  if (!isLast) return;
  __shared__ float pooled[256];
  __shared__ float gpart[8][128];
  __shared__ float g1[128];
  if (tid < 128) {
    float s = 0.f;
#pragma unroll
    for (int bk = 0; bk < 4; bk++) s += atomicAdd(&ws[OFF_PSUM + bk * 128 + tid], 0.f);
    pooled[tid] = s * (1.f / (float)N_NODES);
  } else if (tid < 256) {
    int c = tid - 128;
    int mx = 0x80000000;
#pragma unroll
    for (int bk = 0; bk < 4; bk++) mx = max(mx, atomicAdd(&((int*)ws)[OFF_PMAX + bk * 128 + c], 0));
    int bits = mx >= 0 ? mx : (mx ^ 0x7fffffff);
    pooled[tid] = __int_as_float(bits);
  }
  __syncthreads();
  {
    int c = tid & 127, g = tid >> 7;   // g 0..7
    float acc2 = 0.f;
#pragma unroll 8
    for (int k = g * 32; k < g * 32 + 32; k++) acc2 += pooled[k] * gW1[k * 128 + c];
    gpart[g][c] = acc2;
  }
  __syncthreads();
  if (tid < 128) {
    float s = gb1[tid];
#pragma unroll
    for (int g = 0; g < 8; g++) s += gpart[g][tid];
    g1[tid] = fmaxf(s, 0.f);
  }
  __syncthreads();
  {
    int c = tid & 127, g = tid >> 7;
    float acc2 = 0.f;
#pragma unroll 8
    for (int k = g * 16; k < g * 16 + 16; k++) acc2 += g1[k] * gW2[k * 128 + c];
    gpart[g][c] = acc2;
  }
  __syncthreads();
  if (tid < 128) {
    float s = gb2[tid];
#pragma unroll
    for (int g = 0; g < 8; g++) s += gpart[g][tid];
    out[N_NODES * HDIM + tid] = s;
  }
}

extern "C" void kernel_launch(void* const* d_in, const int* in_sizes, int n_in,
                              void* d_out, int out_size, void* d_ws, size_t ws_size,
                              hipStream_t stream) {
  const float* bfeat = (const float*)d_in[0];
  const int*   rid   = (const int*)d_in[1];
  const int*   bsrc  = (const int*)d_in[2];
  const int*   bdst  = (const int*)d_in[3];
  const float* bw    = (const float*)d_in[4];
  const int*   ppin  = (const int*)d_in[5];
  const int*   pblk  = (const int*)d_in[6];
  const float* pw    = (const float*)d_in[7];
  const float* pins  = (const float*)d_in[8];
  const float* area  = (const float*)d_in[9];
  const float* remb  = (const float*)d_in[10];
  const float* iemb  = (const float*)d_in[11];
  const float* inW1  = (const float*)d_in[12];
  const float* inb1  = (const float*)d_in[13];
  const float* inW2  = (const float*)d_in[14];
  const float* inb2  = (const float*)d_in[15];
  const float* bW1   = (const float*)d_in[16];
  const float* bb1   = (const float*)d_in[17];
  const float* bW2   = (const float*)d_in[18];
  const float* bb2   = (const float*)d_in[19];
  const float* pW1   = (const float*)d_in[20];
  const float* pb1   = (const float*)d_in[21];
  const float* pW2   = (const float*)d_in[22];
  const float* pb2   = (const float*)d_in[23];
  const float* sW    = (const float*)d_in[24];
  const float* sb    = (const float*)d_in[25];
  const float* lng   = (const float*)d_in[26];
  const float* lnb   = (const float*)d_in[27];
  const float* gW1   = (const float*)d_in[28];
  const float* gb1   = (const float*)d_in[29];
  const float* gW2   = (const float*)d_in[30];
  const float* gb2   = (const float*)d_in[31];

  float* ws  = (float*)d_ws;
  float* out = (float*)d_out;
  unsigned short* hb = (unsigned short*)(ws + OFF_HB);

  hipMemsetAsync(d_ws, 0, OFF_RED * sizeof(float), stream);   // header + cntB + cntP
  setup_kernel<<<1761, 256, 0, stream>>>(bw, pw, area,
                                         bW1, bW2, pW1, pW2, sW, inW1, inW2,
                                         bsrc, bdst, pblk, ppin, pins, ws);
  mid_kernel<<<256, 512, 0, stream>>>(bfeat, rid, remb, iemb, inb1, inb2, bb1, pb1,
                                      ws, hb);
  fused_kernel<<<256, 1024, 0, stream>>>(hb, sb, lng, lnb, bb2, pb2,
                                         gW1, gb1, gW2, gb2, ws, out);
}